// Round 7
// baseline (63.171 us; speedup 1.0000x reference)
//
#include <hip/hip_runtime.h>
#include <math.h>

#define M_  2
#define B_  256
#define L_  1024
#define K_  4
#define S_  20
#define NR_ 100
#define NTERM 7   // Taylor terms T_1..T_7 ; ||mu*Q||inf <= 0.13 -> rem ~2e-11

typedef float f32x4_t __attribute__((ext_vector_type(4)));

__device__ __forceinline__ float softplusf(float x) {
    return x > 20.0f ? x : log1pf(expf(x));
}

// ---------------------------------------------------------------------------
// Kernel 1: per (m,k), compute normalized Q, store T_n = Q^n/n!, n=1..NTERM.
// ---------------------------------------------------------------------------
__global__ __launch_bounds__(512)
void qpow_kernel(const float* __restrict__ exch,   // (M,K,S,S)
                 const float* __restrict__ equil,  // (M,K,S)
                 float*       __restrict__ Qpow)   // (M,K,NTERM,400)
{
    __shared__ float sQ[400];
    __shared__ float sT[2][400];
    __shared__ float sRow[20];

    const int blk = blockIdx.x;          // mm*K_ + kk
    const int kk = blk % K_;
    const int mm = blk / K_;
    const int tid = threadIdx.x;
    const bool act = tid < 400;
    const int i = tid / 20;
    const int j = tid - i * 20;

    float p[20];
    float Q0 = 0.0f, rowsum = 0.0f;

    if (act) {
        const float* eq = equil + (mm * K_ + kk) * S_;
        float mx = eq[0];
        #pragma unroll
        for (int z = 1; z < 20; ++z) mx = fmaxf(mx, eq[z]);
        float s = 0.0f;
        #pragma unroll
        for (int z = 0; z < 20; ++z) { p[z] = expf(eq[z] - mx); s += p[z]; }
        const float inv = 1.0f / s;
        #pragma unroll
        for (int z = 0; z < 20; ++z) p[z] *= inv;

        const float* Kx = exch + (mm * K_ + kk) * S_ * S_;
        float R = (i == j) ? 0.0f : softplusf(0.5f * (Kx[i * 20 + j] + Kx[j * 20 + i]));
        Q0 = R * p[j];
        sQ[tid] = Q0;
    }
    __syncthreads();

    if (act) {
        rowsum = 0.0f;
        #pragma unroll
        for (int z = 0; z < 20; ++z) rowsum += sQ[i * 20 + z];
        if (j == 0) sRow[i] = rowsum;
    }
    __syncthreads();

    float* Tout = Qpow + (size_t)blk * (NTERM * 400);
    if (act) {
        float mue = 0.0f;
        #pragma unroll
        for (int z = 0; z < 20; ++z) mue += p[z] * sRow[z];
        float q = (Q0 - ((i == j) ? rowsum : 0.0f)) / fmaxf(mue, 1e-16f);
        sQ[tid] = q;
        sT[0][tid] = q;
        Tout[tid] = q;       // T_1 = Q
    }
    __syncthreads();

    int cur = 0;
    for (int n = 2; n <= NTERM; ++n) {
        if (act) {
            float acc = 0.0f;
            #pragma unroll
            for (int z = 0; z < 20; ++z) acc += sT[cur][i * 20 + z] * sQ[z * 20 + j];
            acc /= (float)n;
            sT[cur ^ 1][tid] = acc;
            Tout[(n - 1) * 400 + tid] = acc;   // T_n = Q^n / n!
        }
        __syncthreads();
        cur ^= 1;
    }
}

// ---------------------------------------------------------------------------
// Kernel 2: P[m,r,k] = I + sum_n mu^n T_n  (linear combo, no matmuls).
// ---------------------------------------------------------------------------
__global__ __launch_bounds__(512)
void pbuild_kernel(const float* __restrict__ Qpow,  // (M,K,NTERM,400)
                   const float* __restrict__ tauk,  // (M,NR)
                   const float* __restrict__ pmrk,  // (M,K)
                   float*       __restrict__ Pws)   // (M,NR,K,400)
{
    const int blk = blockIdx.x;          // mm*NR*K + rr*K + kk
    const int kk = blk % K_;
    const int rr = (blk / K_) % NR_;
    const int mm = blk / (K_ * NR_);
    const int tid = threadIdx.x;
    if (tid >= 400) return;

    const float mu = softplusf(tauk[mm * NR_ + rr]) * softplusf(pmrk[mm * K_ + kk]);
    const float* T = Qpow + ((size_t)(mm * K_ + kk) * NTERM) * 400 + tid;

    float acc = (tid % 21 == 0) ? 1.0f : 0.0f;   // identity
    float mp = mu;
    #pragma unroll
    for (int n = 0; n < NTERM; ++n) { acc = fmaf(mp, T[n * 400], acc); mp *= mu; }
    Pws[(size_t)blk * 400 + tid] = acc;
}

// ---------------------------------------------------------------------------
// Kernel 3: anc[m,b,l,k*20+s] = sum_z inputs[m,b,l,z] * P[m,ridx[m,b],k,z,s]
// NO LDS, NO barriers. 2048 blocks x 320 threads; block owns 256 rows.
// Thread = (rg 0..15, t 0..19): 4 output cols (k=t/5, s0=(t%5)*4) for 16 rows
// (rg + 16j). P-frag (20 float4) in registers from L2-resident Pws; input rows
// read direct-global (20 same-rg lanes share addresses -> merged + L1 hit).
// Output stores nontemporal (streaming, never re-read).
// ---------------------------------------------------------------------------
#define SPANR 256
#define TPB3  320

__device__ __forceinline__ void fma4(float4& a, float s, const float4& p) {
    a.x = fmaf(s, p.x, a.x);
    a.y = fmaf(s, p.y, a.y);
    a.z = fmaf(s, p.z, a.z);
    a.w = fmaf(s, p.w, a.w);
}

__device__ __forceinline__ void nt_store4(float* dst, const float4& v) {
    f32x4_t w;
    w.x = v.x; w.y = v.y; w.z = v.z; w.w = v.w;
    __builtin_nontemporal_store(w, (f32x4_t*)dst);
}

__global__ __launch_bounds__(TPB3)
void einsum_kernel(const float* __restrict__ inp,  // (M,B,L,S)
                   const float* __restrict__ Pws,  // (M,NR,K,400)
                   const int*   __restrict__ ridx, // (M,B)
                   float*       __restrict__ out)  // (M,B,L,K*S)
{
    const int bx      = blockIdx.x;
    const int quarter = bx & 3;            // L_/SPANR = 4
    const int mb      = bx >> 2;           // 0..511
    const int mm      = mb >> 8;
    const int tid     = threadIdx.x;
    const int t       = tid % 20;
    const int rg      = tid / 20;          // 0..15
    const int k       = t / 5;
    const int s0      = (t % 5) * 4;

    const int r = ridx[mb];                // block-uniform

    // P-frag: 20 rows (z) x 4 cols -> 20 float4 in registers (L2-resident src)
    const float* Pbase = Pws + ((size_t)(mm * NR_ + r) * K_ + k) * 400 + s0;
    float4 Pf[20];
    #pragma unroll
    for (int z = 0; z < 20; ++z)
        Pf[z] = *(const float4*)(Pbase + z * 20);

    const size_t row0 = (size_t)mb * L_ + (size_t)quarter * SPANR;
    const float* inb = inp + row0 * 20;
    float*       ob  = out + row0 * 80 + k * 20 + s0;

    #pragma unroll 1
    for (int c = 0; c < 8; ++c) {          // 8 batches x 2 rows = 16 rows
        const int l0 = rg + (c * 2 + 0) * 16;
        const int l1 = rg + (c * 2 + 1) * 16;
        float4 a0 = make_float4(0.f, 0.f, 0.f, 0.f);
        float4 a1 = make_float4(0.f, 0.f, 0.f, 0.f);

        #pragma unroll
        for (int z4 = 0; z4 < 5; ++z4) {
            const float4 v0 = *(const float4*)(inb + l0 * 20 + z4 * 4);
            const float4 v1 = *(const float4*)(inb + l1 * 20 + z4 * 4);
            fma4(a0, v0.x, Pf[z4 * 4 + 0]);
            fma4(a0, v0.y, Pf[z4 * 4 + 1]);
            fma4(a0, v0.z, Pf[z4 * 4 + 2]);
            fma4(a0, v0.w, Pf[z4 * 4 + 3]);
            fma4(a1, v1.x, Pf[z4 * 4 + 0]);
            fma4(a1, v1.y, Pf[z4 * 4 + 1]);
            fma4(a1, v1.z, Pf[z4 * 4 + 2]);
            fma4(a1, v1.w, Pf[z4 * 4 + 3]);
        }

        nt_store4(ob + (size_t)l0 * 80, a0);
        nt_store4(ob + (size_t)l1 * 80, a1);
    }
}

// ---------------------------------------------------------------------------
extern "C" void kernel_launch(void* const* d_in, const int* in_sizes, int n_in,
                              void* d_out, int out_size, void* d_ws, size_t ws_size,
                              hipStream_t stream) {
    const float* inp   = (const float*)d_in[0];  // (M,B,L,S)
    const float* tauk  = (const float*)d_in[1];  // (M,NR)
    const float* exch  = (const float*)d_in[2];  // (M,K,S,S)
    const float* equil = (const float*)d_in[3];  // (M,K,S)
    const float* pmrk  = (const float*)d_in[4];  // (M,K)
    const int*   ridx  = (const int*)d_in[5];    // (M,B)
    float* outp = (float*)d_out;

    float* Qpow = (float*)d_ws;                          // 89.6 KB
    float* Pws  = Qpow + (size_t)M_ * K_ * NTERM * 400;  // 1.28 MB

    qpow_kernel<<<M_ * K_, 512, 0, stream>>>(exch, equil, Qpow);
    pbuild_kernel<<<M_ * NR_ * K_, 512, 0, stream>>>(Qpow, tauk, pmrk, Pws);
    einsum_kernel<<<M_ * B_ * (L_ / SPANR), TPB3, 0, stream>>>(inp, Pws, ridx, outp);
}